// Round 5
// baseline (133.791 us; speedup 1.0000x reference)
//
#include <hip/hip_runtime.h>

// out[m][e*5+c] = x[m,c]*w_c[e] + (b_c[e] + ot[c][e]);  M=65536, E=512
// Pure HBM-write-bound (640 MiB f32 out). Ladder so far:
//   R1 136us: barrier-per-2-rows (vmcnt(0) drains)          ~4.9 TB/s
//   R2 242us: per-row global x loads share in-order vmcnt with stores
//   R4 131us: pure store stream, 2048 blocks x 32 rows      ~5.1 TB/s
// R4 lesson: store-stream purity was worth only ~4%; remaining ~30us vs the
// 6.7 TB/s fill ceiling is block-granular tail skew (~12us), 2048x prologue
// cost, and barrier drains. R5 structure:
//   - persistent: 512 blocks (2/CU) x 640 threads; block b owns rows
//     b + k*512, k=0..127  -> EXACTLY equal work, zero tail skew
//   - prologue (tables->LDS->regs) runs 512x not 2048x
//   - x double-buffered in LDS, groups of 8 rows; T14 split: issue next
//     group's 40 scattered x loads EARLY, ds_write LATE after the stores
//     (counted vmcnt, no drain)
//   - group barrier = raw s_barrier + lgkmcnt(0) only — vmcnt never drained
//     inside the loop; main loop is a pure global_store_dwordx4 stream.

#define THREADS 640
#define GRID    512
#define GROUPS  16          // 16 groups x 8 rows = 128 rows per block

__global__ __launch_bounds__(THREADS) void pc_kernel(
    const float* __restrict__ x,
    const float* __restrict__ w_bet,  const float* __restrict__ b_bet,
    const float* __restrict__ w_stk,  const float* __restrict__ b_stk,
    const float* __restrict__ w_call, const float* __restrict__ b_call,
    const float* __restrict__ w_odds, const float* __restrict__ b_odds,
    const float* __restrict__ ot,
    float* __restrict__ out)
{
    __shared__ float tw[2560];      // tw[c*512+e] = w_c[e]
    __shared__ float tb[2560];      // tb[c*512+e] = b_c[e] + ot[c][e]
    __shared__ float xb[2][40];     // double-buffered x slice (8 rows x 5)

    const int tid = threadIdx.x;
    const int b   = blockIdx.x;

    // ---- one-time prologue: stage tables + group-0 x slice ----
    {
        const int c  = tid >> 7;    // 0..4
        const int e0 = (tid & 127) * 4;
        const float* wp; const float* bp;
        if      (c == 0) { wp = w_bet;  bp = b_bet;  }
        else if (c == 1) { wp = w_stk;  bp = b_stk;  }
        else if (c == 2) { wp = w_stk;  bp = b_stk;  }
        else if (c == 3) { wp = w_call; bp = b_call; }
        else             { wp = w_odds; bp = b_odds; }
        float4 w4 = *reinterpret_cast<const float4*>(wp + e0);
        float4 b4 = *reinterpret_cast<const float4*>(bp + e0);
        float4 o4 = *reinterpret_cast<const float4*>(ot + c * 512 + e0);
        *reinterpret_cast<float4*>(tw + c * 512 + e0) = w4;
        float4 bb;
        bb.x = b4.x + o4.x; bb.y = b4.y + o4.y;
        bb.z = b4.z + o4.z; bb.w = b4.w + o4.w;
        *reinterpret_cast<float4*>(tb + c * 512 + e0) = bb;

        if (tid < 40) {             // rows b + j*GRID, j = 0..7
            int j = tid / 5, cc = tid - 5 * j;
            xb[0][tid] = x[(size_t)(b + j * GRID) * 5 + cc];
        }
    }
    __syncthreads();                // full barrier OK in prologue

    // ---- per-thread row-invariant table values for words 4t..4t+3 ----
    float wv[4], bv[4];
    int   cj[4];
#pragma unroll
    for (int j = 0; j < 4; ++j) {
        int w = 4 * tid + j;        // word within a row, 0..2559
        int e = w / 5;              // magic-mul (setup only)
        int c = w - 5 * e;
        cj[j] = c;
        wv[j] = tw[c * 512 + e];
        bv[j] = tb[c * 512 + e];
    }

    float4* outv = reinterpret_cast<float4*>(out);
    const int obase = b * 640 + tid;        // float4 index of row-slot

    for (int g = 0; g < GROUPS; ++g) {
        const int p = g & 1;
        const float* xr0 = &xb[p][0];

        // T14: issue next group's x loads EARLY (lanes 0..39 of wave 0)
        float xs;
        const bool stager = (tid < 40) && (g + 1 < GROUPS);
        if (stager) {
            int j = tid / 5, cc = tid - 5 * j;
            xs = x[(size_t)(b + (8 * (g + 1) + j) * GRID) * 5 + cc];
        }

        // 8 rows: 4 ds_read_b32 + 4 FMA + 1 coalesced store128 each
#pragma unroll
        for (int j = 0; j < 8; ++j) {
            const float* xr = xr0 + j * 5;
            float4 v;
            v.x = fmaf(xr[cj[0]], wv[0], bv[0]);
            v.y = fmaf(xr[cj[1]], wv[1], bv[1]);
            v.z = fmaf(xr[cj[2]], wv[2], bv[2]);
            v.w = fmaf(xr[cj[3]], wv[3], bv[3]);
            outv[obase + (8 * g + j) * (GRID * 640)] = v;
        }

        // T14: ds_write LATE (counted vmcnt wait — stores NOT drained)
        if (stager) xb[p ^ 1][tid] = xs;

        // lgkm-only barrier: no vmcnt(0) drain of the store stream
        asm volatile("s_waitcnt lgkmcnt(0)" ::: "memory");
        __builtin_amdgcn_s_barrier();
    }
}

extern "C" void kernel_launch(void* const* d_in, const int* in_sizes, int n_in,
                              void* d_out, int out_size, void* d_ws, size_t ws_size,
                              hipStream_t stream) {
    const float* x      = (const float*)d_in[0];
    const float* w_bet  = (const float*)d_in[1];
    const float* b_bet  = (const float*)d_in[2];
    const float* w_stk  = (const float*)d_in[3];
    const float* b_stk  = (const float*)d_in[4];
    const float* w_call = (const float*)d_in[5];
    const float* b_call = (const float*)d_in[6];
    const float* w_odds = (const float*)d_in[7];
    const float* b_odds = (const float*)d_in[8];
    const float* ot     = (const float*)d_in[9];
    float* out = (float*)d_out;

    pc_kernel<<<GRID, THREADS, 0, stream>>>(x, w_bet, b_bet, w_stk, b_stk,
                                            w_call, b_call, w_odds, b_odds,
                                            ot, out);
}